// Round 23
// baseline (448.401 us; speedup 1.0000x reference)
//
#include <hip/hip_runtime.h>
#include <math.h>

#define D_MODEL   2048
#define D_INNER   4096
#define XBC_DIM   4224
#define D_IN_PROJ 8384
#define N_ZX      8320
#define NH    64
#define HD    64
#define DS    64
#define LCH   256
#define NCH   8
#define LSEQ  2048
#define TTOK  4096
#define EPS_R 1.1920929e-07f

#define XT_S 264
#define WL_S 72
#define GEMM_IN_BLKS ((N_ZX / 128) * (TTOK / 128))   // 2080

typedef unsigned short u16;
typedef unsigned int   u32;
typedef _Float16 f16x8 __attribute__((ext_vector_type(8)));
typedef _Float16 f16x4 __attribute__((ext_vector_type(4)));
typedef float    f4v   __attribute__((ext_vector_type(4)));

__device__ __forceinline__ float4 f16_ld4(const _Float16* c, size_t idx) {
    f16x4 v = *(const f16x4*)(c + idx);
    return make_float4((float)v[0], (float)v[1], (float)v[2], (float)v[3]);
}
__device__ __forceinline__ f16x8 cvt8(float4 a, float4 b) {
    f16x8 r;
    r[0] = (_Float16)a.x; r[1] = (_Float16)a.y; r[2] = (_Float16)a.z; r[3] = (_Float16)a.w;
    r[4] = (_Float16)b.x; r[5] = (_Float16)b.y; r[6] = (_Float16)b.z; r[7] = (_Float16)b.w;
    return r;
}
__device__ __forceinline__ float fexp(float x)  { return __expf(x); }
__device__ __forceinline__ float fsilu(float x) { return x / (1.f + __expf(-x)); }
__device__ __forceinline__ int xcd_swz(int orig, int nwg) {
    int cpx = nwg >> 3;
    return (orig & 7) * cpx + (orig >> 3);
}
__device__ __forceinline__ void gload16(const _Float16* g, _Float16* l) {
    __builtin_amdgcn_global_load_lds(
        (const __attribute__((address_space(1))) u32*)g,
        (__attribute__((address_space(3))) u32*)l, 16, 0, 0);
}

// ---- one merged f32 -> f16 pre-conversion (x16 | win16 | wout16*nw) -----
#define NX8  ((size_t)TTOK * D_MODEL / 8)
#define NW8  ((size_t)N_ZX * D_MODEL / 8)
#define NO8  ((size_t)D_MODEL * D_INNER / 8)
__global__ __launch_bounds__(256) void cvt_all_kernel(const float* __restrict__ x,
                                                      const float* __restrict__ w_in,
                                                      const float* __restrict__ w_out,
                                                      const float* __restrict__ nw,
                                                      _Float16* __restrict__ x16,
                                                      _Float16* __restrict__ win16,
                                                      _Float16* __restrict__ wout16) {
    size_t i = (size_t)blockIdx.x * 256 + threadIdx.x;
    if (i < NX8) {
        size_t base = i * 8;
        float4 a = *(const float4*)(x + base);
        float4 b = *(const float4*)(x + base + 4);
        *(f16x8*)(x16 + base) = cvt8(a, b);
    } else if (i < NX8 + NW8) {
        size_t base = (i - NX8) * 8;
        float4 a = *(const float4*)(w_in + base);
        float4 b = *(const float4*)(w_in + base + 4);
        *(f16x8*)(win16 + base) = cvt8(a, b);
    } else if (i < NX8 + NW8 + NO8) {
        size_t base = (i - NX8 - NW8) * 8;
        int k = (int)(base & 4095);
        float4 a = *(const float4*)(w_out + base);
        float4 b = *(const float4*)(w_out + base + 4);
        float4 na = *(const float4*)(nw + k);
        float4 nb = *(const float4*)(nw + k + 4);
        a.x *= na.x; a.y *= na.y; a.z *= na.z; a.w *= na.w;
        b.x *= nb.x; b.y *= nb.y; b.z *= nb.z; b.w *= nb.w;
        *(f16x8*)(wout16 + base) = cvt8(a, b);
    }
}

// ===== UNION: dtproj (blocks 0..255) + in_proj GEMM (blocks 256..2335) ===
__global__ __launch_bounds__(256) void gemm_in_dt(const _Float16* __restrict__ A,
                                                  const _Float16* __restrict__ W,
                                                  _Float16* __restrict__ zf,
                                                  _Float16* __restrict__ cbuf,
                                                  const float* __restrict__ x,
                                                  const float* __restrict__ w_in,
                                                  const float* __restrict__ dt_bias,
                                                  float* __restrict__ dt_buf) {
    __shared__ __align__(16) char smem[65536];
    const int tid = threadIdx.x;

    if (blockIdx.x < 256) {
        float* Xs = (float*)smem;
        float* Ws = (float*)(smem + 4096);
        int t0 = blockIdx.x * 16;
        int h = tid & 63, trow = tid >> 6;
        float acc[4] = {0.f, 0.f, 0.f, 0.f};
        const float* wdt = w_in + (size_t)(D_INNER + XBC_DIM) * D_MODEL;

        for (int k0 = 0; k0 < D_MODEL; k0 += 64) {
            __syncthreads();
            {
                int r = tid >> 4, c4 = (tid & 15) * 4;
                *(float4*)&Xs[r * 64 + c4] =
                    *(const float4*)(x + (size_t)(t0 + r) * D_MODEL + k0 + c4);
            }
            #pragma unroll
            for (int i = 0; i < 4; ++i) {
                int ff = tid + i * 256;
                int r = ff >> 4, c4 = (ff & 15) * 4;
                float4 v = *(const float4*)(wdt + (size_t)r * D_MODEL + k0 + c4);
                Ws[r * 65 + c4 + 0] = v.x; Ws[r * 65 + c4 + 1] = v.y;
                Ws[r * 65 + c4 + 2] = v.z; Ws[r * 65 + c4 + 3] = v.w;
            }
            __syncthreads();
            #pragma unroll 16
            for (int k = 0; k < 64; ++k) {
                float wv = Ws[h * 65 + k];
                #pragma unroll
                for (int i = 0; i < 4; ++i)
                    acc[i] += Xs[(trow + i * 4) * 64 + k] * wv;
            }
        }
        float bias = dt_bias[h];
        #pragma unroll
        for (int i = 0; i < 4; ++i) {
            float xv = acc[i] + bias;
            float sp = (xv > 20.f) ? xv : log1pf(expf(xv));
            dt_buf[(size_t)(t0 + trow + i * 4) * 64 + h] = sp;
        }
        return;
    }

    _Float16* lsA = (_Float16*)smem;
    _Float16* lsB = (_Float16*)(smem + 32768);
    const int lane = tid & 63, w = tid >> 6;
    int swz = xcd_swz((int)blockIdx.x - 256, GEMM_IN_BLKS);
    int band = swz / 260, idx = swz % 260;
    const int row0 = (band * 4 + (idx & 3)) * 128;
    const int col0 = (idx >> 2) * 128;
    const int wr = w >> 1, wc = w & 1;
    const int fr = lane & 15, fq = lane >> 4;

    auto stage = [&](int buf, int k0) {
        #pragma unroll
        for (int i = 0; i < 4; ++i) {
            int obase = i * 4096 + w * 1024;
            int o = obase + lane * 16;
            int row = o >> 7, b0 = o & 127;
            int lb = b0 ^ ((row & 7) << 4);
            gload16(A + (size_t)(row0 + row) * D_MODEL + k0 + (lb >> 1),
                    lsA + buf * 8192 + (obase >> 1));
            gload16(W + (size_t)(col0 + row) * D_MODEL + k0 + (lb >> 1),
                    lsB + buf * 8192 + (obase >> 1));
        }
    };

    f4v acc[4][4];
    #pragma unroll
    for (int mi = 0; mi < 4; ++mi)
        #pragma unroll
        for (int ni = 0; ni < 4; ++ni) acc[mi][ni] = (f4v){0.f, 0.f, 0.f, 0.f};

    stage(0, 0);
    __syncthreads();
    int cur = 0;
    for (int k0 = 0; k0 < D_MODEL; k0 += 64) {
        if (k0 + 64 < D_MODEL) stage(cur ^ 1, k0 + 64);
        f16x8 ah[4][2];
        #pragma unroll
        for (int mi = 0; mi < 4; ++mi)
            #pragma unroll
            for (int kf = 0; kf < 2; ++kf) {
                int r = wr * 64 + mi * 16 + fr;
                int pb = (kf * 64 + fq * 16) ^ ((r & 7) << 4);
                ah[mi][kf] = *(const f16x8*)((const char*)lsA + cur * 16384 + r * 128 + pb);
            }
        #pragma unroll
        for (int ni = 0; ni < 4; ++ni) {
            #pragma unroll
            for (int kf = 0; kf < 2; ++kf) {
                int rb = wc * 64 + ni * 16 + fr;
                int pb = (kf * 64 + fq * 16) ^ ((rb & 7) << 4);
                f16x8 bh = *(const f16x8*)((const char*)lsB + cur * 16384 + rb * 128 + pb);
                #pragma unroll
                for (int mi = 0; mi < 4; ++mi)
                    acc[mi][ni] = __builtin_amdgcn_mfma_f32_16x16x32_f16(ah[mi][kf], bh, acc[mi][ni], 0, 0, 0);
            }
        }
        __syncthreads();
        cur ^= 1;
    }

    const int orow = fq * 4;
    #pragma unroll
    for (int mi = 0; mi < 4; ++mi)
        #pragma unroll
        for (int ni = 0; ni < 4; ++ni) {
            int r = row0 + wr * 64 + mi * 16 + orow;
            int cc = col0 + wc * 64 + ni * 16 + fr;
            if (col0 < D_INNER) {
                #pragma unroll
                for (int j = 0; j < 4; ++j)
                    zf[(size_t)(r + j) * D_INNER + cc] = (_Float16)acc[mi][ni][j];
            } else {
                #pragma unroll
                for (int j = 0; j < 4; ++j)
                    cbuf[(size_t)(r + j) * XBC_DIM + (cc - D_INNER)] = (_Float16)acc[mi][ni][j];
            }
        }
}

// ===== UNION: scan (blocks 0..1023) + bcconv (blocks 1024..3071) =========
__global__ __launch_bounds__(256) void scan_bc_kernel(const float* __restrict__ dt_buf,
                                                      const float* __restrict__ A_log,
                                                      float* __restrict__ acs,
                                                      const _Float16* __restrict__ cbuf,
                                                      const float* __restrict__ cw,
                                                      const float* __restrict__ cb,
                                                      _Float16* __restrict__ bc) {
    int tid = threadIdx.x;
    if (blockIdx.x < 1024) {
        int bh = blockIdx.x >> 3, c = blockIdx.x & 7;
        int b = bh >> 6, h = bh & 63;
        float Ah = -expf(A_log[h]);
        __shared__ float s[256];
        int t = b * LSEQ + c * LCH + tid;
        float a = Ah * dt_buf[t * 64 + h];
        s[tid] = a;
        __syncthreads();
        for (int off = 1; off < 256; off <<= 1) {
            float v = (tid >= off) ? s[tid - off] : 0.f;
            __syncthreads();
            s[tid] += v;
            __syncthreads();
        }
        acs[(size_t)bh * LSEQ + c * LCH + tid] = s[tid];
    } else {
        int t = ((int)blockIdx.x - 1024) * 2 + (tid >> 7);
        int chl = tid & 127;
        int b = t >> 11, lp = t & 2047;
        int ch = D_INNER + chl;
        float acc = cb[ch];
        #pragma unroll
        for (int j = 0; j < 4; ++j) {
            int lj = lp - 3 + j;
            if (lj >= 0)
                acc += cw[ch * 4 + j] * (float)cbuf[(size_t)(b * LSEQ + lj) * XBC_DIM + ch];
        }
        bc[(size_t)t * 128 + chl] = (_Float16)fsilu(acc);
    }
}

// out_proj with fused rstd; band-col-major mapping
__global__ __launch_bounds__(256) void gemm_out16(const _Float16* __restrict__ A,
                                                  const _Float16* __restrict__ W,
                                                  float* __restrict__ C,
                                                  const float* __restrict__ usq) {
    __shared__ __align__(16) _Float16 lsA[2][128 * 64];
    __shared__ __align__(16) _Float16 lsB[2][128 * 64];
    __shared__ float rstd_l[128];
    const int tid = threadIdx.x, lane = tid & 63, w = tid >> 6;
    int swz = xcd_swz(blockIdx.x, (D_MODEL / 128) * (TTOK / 128));
    int band = swz / 64, idx = swz % 64;
    const int row0 = (band * 4 + (idx & 3)) * 128;
    const int col0 = (idx >> 2) * 128;
    const int wr = w >> 1, wc = w & 1;
    const int fr = lane & 15, fq = lane >> 4;

    auto stage = [&](int buf, int k0) {
        #pragma unroll
        for (int i = 0; i < 4; ++i) {
            int obase = i * 4096 + w * 1024;
            int o = obase + lane * 16;
            int row = o >> 7, b0 = o & 127;
            int lb = b0 ^ ((row & 7) << 4);
            gload16(A + (size_t)(row0 + row) * D_INNER + k0 + (lb >> 1), &lsA[buf][obase >> 1]);
            gload16(W + (size_t)(col0 + row) * D_INNER + k0 + (lb >> 1), &lsB[buf][obase >> 1]);
        }
    };

    if (tid < 128) {
        const float* uq = usq + (size_t)(row0 + tid) * 64;
        float s = 0.f;
        #pragma unroll
        for (int i = 0; i < 16; ++i) {
            float4 v = *(const float4*)(uq + i * 4);
            s += v.x + v.y + v.z + v.w;
        }
        rstd_l[tid] = rsqrtf(s / 4096.f + EPS_R);
    }

    f4v acc[4][4];
    #pragma unroll
    for (int mi = 0; mi < 4; ++mi)
        #pragma unroll
        for (int ni = 0; ni < 4; ++ni) acc[mi][ni] = (f4v){0.f, 0.f, 0.f, 0.f};

    stage(0, 0);
    __syncthreads();
    int cur = 0;
    for (int k0 = 0; k0 < D_INNER; k0 += 64) {
        if (k0 + 64 < D_INNER) stage(cur ^ 1, k0 + 64);
        f16x8 ah[4][2];
        #pragma unroll
        for (int mi = 0; mi < 4; ++mi)
            #pragma unroll
            for (int kf = 0; kf < 2; ++kf) {
                int r = wr * 64 + mi * 16 + fr;
                int pb = (kf * 64 + fq * 16) ^ ((r & 7) << 4);
                ah[mi][kf] = *(const f16x8*)((const char*)&lsA[cur][0] + r * 128 + pb);
            }
        #pragma unroll
        for (int ni = 0; ni < 4; ++ni) {
            #pragma unroll
            for (int kf = 0; kf < 2; ++kf) {
                int rb = wc * 64 + ni * 16 + fr;
                int pb = (kf * 64 + fq * 16) ^ ((rb & 7) << 4);
                f16x8 bh = *(const f16x8*)((const char*)&lsB[cur][0] + rb * 128 + pb);
                #pragma unroll
                for (int mi = 0; mi < 4; ++mi)
                    acc[mi][ni] = __builtin_amdgcn_mfma_f32_16x16x32_f16(ah[mi][kf], bh, acc[mi][ni], 0, 0, 0);
            }
        }
        __syncthreads();
        cur ^= 1;
    }

    const int orow = fq * 4;
    #pragma unroll
    for (int mi = 0; mi < 4; ++mi)
        #pragma unroll
        for (int ni = 0; ni < 4; ++ni) {
            int rl = wr * 64 + mi * 16 + orow;
            int cc = col0 + wc * 64 + ni * 16 + fr;
            #pragma unroll
            for (int j = 0; j < 4; ++j)
                C[(size_t)(row0 + rl + j) * D_MODEL + cc] = acc[mi][ni][j] * rstd_l[rl + j];
        }
}

// ===== MFMA chunk states + XT dump; wdec folded into BT ==================
__global__ __launch_bounds__(256) void chunkstate_mfma(const _Float16* __restrict__ cbuf,
                                                       const _Float16* __restrict__ bc,
                                                       const float* __restrict__ cw,
                                                       const float* __restrict__ cb,
                                                       const float* __restrict__ dt_buf,
                                                       const float* __restrict__ acs,
                                                       float* __restrict__ states,
                                                       _Float16* __restrict__ xts) {
    const int h = blockIdx.x & 63;
    const int c = (blockIdx.x >> 6) & 7;
    const int b = blockIdx.x >> 9;
    const int tbase = b * LSEQ + c * LCH;
    const int tid = threadIdx.x, lane = tid & 63, w = tid >> 6;
    const int fr = lane & 15, fq = lane >> 4;

    __shared__ __align__(16) _Float16 XT[64][XT_S];   // unweighted X^T
    __shared__ __align__(16) _Float16 BT[64][XT_S];   // wdec-weighted B^T
    __shared__ float acs_s[256], dts[256], wdec[256];

    const float* acs_blk = acs + (size_t)(b * 64 + h) * LSEQ + c * LCH;
    acs_s[tid] = acs_blk[tid];
    dts[tid] = dt_buf[(size_t)(tbase + tid) * 64 + h];
    __syncthreads();
    const float acs_last = acs_s[LCH - 1];
    wdec[tid] = fexp(acs_last - acs_s[tid]) * dts[tid];

    #pragma unroll 4
    for (int i = 0; i < 16; ++i) {
        int u = tid + i * 256;
        int s = u >> 4, pq = (u & 15) * 4;
        int lp = c * LCH + s;
        int ch0 = h * HD + pq;
        float tp[4][4];
        #pragma unroll
        for (int k = 0; k < 4; ++k)
            *(float4*)tp[k] = *(const float4*)(cw + (size_t)(ch0 + k) * 4);
        float a0 = cb[ch0], a1 = cb[ch0 + 1], a2 = cb[ch0 + 2], a3 = cb[ch0 + 3];
        #pragma unroll
        for (int j = 0; j < 4; ++j) {
            int lj = lp - 3 + j;
            if (lj >= 0) {
                float4 v = f16_ld4(cbuf, (size_t)(b * LSEQ + lj) * XBC_DIM + ch0);
                a0 += tp[0][j] * v.x; a1 += tp[1][j] * v.y;
                a2 += tp[2][j] * v.z; a3 += tp[3][j] * v.w;
            }
        }
        XT[pq + 0][s] = (_Float16)fsilu(a0);
        XT[pq + 1][s] = (_Float16)fsilu(a1);
        XT[pq + 2][s] = (_Float16)fsilu(a2);
        XT[pq + 3][s] = (_Float16)fsilu(a3);
    }
    __syncthreads();
    #pragma unroll 4
    for (int i = 0; i < 16; ++i) {
        int u = tid + i * 256;
        int s = u >> 4, n4 = (u & 15) * 4;
        f16x4 v = *(const f16x4*)(bc + (size_t)(tbase + s) * 128 + n4);
        float wd = wdec[s];
        BT[n4 + 0][s] = (_Float16)((float)v[0] * wd);
        BT[n4 + 1][s] = (_Float16)((float)v[1] * wd);
        BT[n4 + 2][s] = (_Float16)((float)v[2] * wd);
        BT[n4 + 3][s] = (_Float16)((float)v[3] * wd);
    }
    __syncthreads();

    f4v acc[4];
    #pragma unroll
    for (int nf = 0; nf < 4; ++nf) acc[nf] = (f4v){0.f, 0.f, 0.f, 0.f};
    __builtin_amdgcn_s_setprio(1);
    #pragma unroll
    for (int ks = 0; ks < 8; ++ks) {
        f16x8 af = *(const f16x8*)&XT[w * 16 + fr][ks * 32 + fq * 8];
        #pragma unroll
        for (int nf = 0; nf < 4; ++nf) {
            f16x8 bf = *(const f16x8*)&BT[nf * 16 + fr][ks * 32 + fq * 8];
            acc[nf] = __builtin_amdgcn_mfma_f32_16x16x32_f16(af, bf, acc[nf], 0, 0, 0);
        }
    }
    __builtin_amdgcn_s_setprio(0);
    float* sp = states + (size_t)blockIdx.x * 4096;
    #pragma unroll
    for (int nf = 0; nf < 4; ++nf)
        #pragma unroll
        for (int r = 0; r < 4; ++r)
            sp[(size_t)(w * 16 + fq * 4 + r) * 64 + nf * 16 + fr] = acc[nf][r];

    // dump unweighted XT to scratch for ymerged
    {
        _Float16* xd = xts + (size_t)blockIdx.x * 16384 + tid * 64;
        int pp = tid >> 2, s0 = (tid & 3) * 64;
        #pragma unroll
        for (int i = 0; i < 8; ++i)
            *(f16x8*)(xd + i * 8) = *(const f16x8*)&XT[pp][s0 + i * 8];
    }
}

// ----- inter-chunk recurrence per (b,h); in-place ------------------------
__global__ __launch_bounds__(256) void chunkscan_kernel(const float* __restrict__ acs,
                                                        float* __restrict__ states) {
    int b = blockIdx.x >> 6, h = blockIdx.x & 63;
    int tid = threadIdx.x;
    float4 S4[4];
    #pragma unroll
    for (int i = 0; i < 4; ++i) S4[i] = make_float4(0.f, 0.f, 0.f, 0.f);
    const float* acs_blk = acs + (size_t)blockIdx.x * LSEQ;
    for (int c = 0; c < NCH; ++c) {
        float d = expf(acs_blk[c * LCH + LCH - 1]);
        float4* sp = (float4*)(states + ((size_t)(b * NCH + c) * NH + h) * 4096 + tid * 16);
        float4 t4[4];
        #pragma unroll
        for (int i = 0; i < 4; ++i) t4[i] = sp[i];
        #pragma unroll
        for (int i = 0; i < 4; ++i) sp[i] = S4[i];
        #pragma unroll
        for (int i = 0; i < 4; ++i) {
            S4[i].x = d * S4[i].x + t4[i].x;
            S4[i].y = d * S4[i].y + t4[i].y;
            S4[i].z = d * S4[i].z + t4[i].z;
            S4[i].w = d * S4[i].w + t4[i].w;
        }
    }
}

// ===== MFMA ymerged (4-wave); XT fragments straight from L2-hot xts ======
// LDS 72.7 -> 38.9 KB (XT removed) -> 3 blocks/CU for wave-imbalance hiding.
__global__ __launch_bounds__(256) void ymerged_mfma(const _Float16* __restrict__ xts,
                                                    const _Float16* __restrict__ bc,
                                                    _Float16* __restrict__ zf,
                                                    const float* __restrict__ dt_buf,
                                                    const float* __restrict__ acs,
                                                    const float* __restrict__ states,
                                                    const float* __restrict__ D_param,
                                                    float* __restrict__ usq) {
    const int h = blockIdx.x & 63;
    const int c = (blockIdx.x >> 6) & 7;
    const int b = blockIdx.x >> 9;
    const int tbase = b * LSEQ + c * LCH;
    const int tid = threadIdx.x, lane = tid & 63, w = tid >> 6;
    const int fr = lane & 15, fq = lane >> 4;
    const _Float16* xbase = xts + (size_t)blockIdx.x * 16384;

    __shared__ __align__(16) _Float16 Wl[4][64][WL_S];
    __shared__ float acs_s[256];
    __shared__ float dts[256];

    const float* acs_blk = acs + (size_t)(b * 64 + h) * LSEQ + c * LCH;
    acs_s[tid] = acs_blk[tid];
    dts[tid] = dt_buf[(size_t)(tbase + tid) * 64 + h];
    __syncthreads();

    f16x8 cf[4][2];
    #pragma unroll
    for (int ls = 0; ls < 4; ++ls)
        #pragma unroll
        for (int kf = 0; kf < 2; ++kf)
            cf[ls][kf] = *(const f16x8*)(bc + (size_t)(tbase + w * 64 + ls * 16 + fr) * 128
                                         + 64 + kf * 32 + fq * 8);

    float acsl[16];
    #pragma unroll
    for (int ls = 0; ls < 4; ++ls)
        #pragma unroll
        for (int r = 0; r < 4; ++r)
            acsl[ls * 4 + r] = acs_s[w * 64 + ls * 16 + fq * 4 + r];

    f4v Y[4][4];
    {
        f16x8 sf[4][2];
        #pragma unroll
        for (int ps = 0; ps < 4; ++ps)
            #pragma unroll
            for (int kf = 0; kf < 2; ++kf) {
                const float* src = states + (size_t)blockIdx.x * 4096
                                 + (ps * 16 + fr) * 64 + kf * 32 + fq * 8;
                sf[ps][kf] = cvt8(*(const float4*)src, *(const float4*)(src + 4));
            }
        f4v yo[4][4];
        __builtin_amdgcn_s_setprio(1);
        #pragma unroll
        for (int ls = 0; ls < 4; ++ls)
            #pragma unroll
            for (int ps = 0; ps < 4; ++ps) {
                yo[ls][ps] = (f4v){0.f, 0.f, 0.f, 0.f};
                yo[ls][ps] = __builtin_amdgcn_mfma_f32_16x16x32_f16(cf[ls][0], sf[ps][0], yo[ls][ps], 0, 0, 0);
                yo[ls][ps] = __builtin_amdgcn_mfma_f32_16x16x32_f16(cf[ls][1], sf[ps][1], yo[ls][ps], 0, 0, 0);
            }
        __builtin_amdgcn_s_setprio(0);
        #pragma unroll
        for (int ls = 0; ls < 4; ++ls)
            #pragma unroll
            for (int ps = 0; ps < 4; ++ps)
                #pragma unroll
                for (int r = 0; r < 4; ++r)
                    Y[ls][ps][r] = fexp(acsl[ls * 4 + r]) * yo[ls][ps][r];
    }

    for (int st = 0; st <= w; ++st) {
        f16x8 bf[4][2];
        #pragma unroll
        for (int ss = 0; ss < 4; ++ss)
            #pragma unroll
            for (int kf = 0; kf < 2; ++kf)
                bf[ss][kf] = *(const f16x8*)(bc + (size_t)(tbase + st * 64 + ss * 16 + fr) * 128
                                             + kf * 32 + fq * 8);
        f4v S[4][4];
        __builtin_amdgcn_s_setprio(1);
        #pragma unroll
        for (int ls = 0; ls < 4; ++ls)
            #pragma unroll
            for (int ss = 0; ss < 4; ++ss) {
                S[ls][ss] = (f4v){0.f, 0.f, 0.f, 0.f};
                S[ls][ss] = __builtin_amdgcn_mfma_f32_16x16x32_f16(cf[ls][0], bf[ss][0], S[ls][ss], 0, 0, 0);
                S[ls][ss] = __builtin_amdgcn_mfma_f32_16x16x32_f16(cf[ls][1], bf[ss][1], S[ls][ss], 0, 0, 0);
            }
        __builtin_amdgcn_s_setprio(0);
        #pragma unroll
        for (int ss = 0; ss < 4; ++ss) {
            int s_idx = st * 64 + ss * 16 + fr;
            float as = acs_s[s_idx];
            float dv = dts[s_idx];
            #pragma unroll
            for (int ls = 0; ls < 4; ++ls)
                #pragma unroll
                for (int r = 0; r < 4; ++r) {
                    int l_idx = w * 64 + ls * 16 + fq * 4 + r;
                    float wv = (s_idx <= l_idx)
                             ? fexp(acsl[ls * 4 + r] - as) * dv * S[ls][ss][r] : 0.f;
                    Wl[w][ls * 16 + fq * 4 + r][ss * 16 + fr] = (_Float16)wv;
                }
        }
        f16x8 wf[4][2], xf[4][2];
        #pragma unroll
        for (int ls = 0; ls < 4; ++ls)
            #pragma unroll
            for (int kf = 0; kf < 2; ++kf)
                wf[ls][kf] = *(const f16x8*)&Wl[w][ls * 16 + fr][kf * 32 + fq * 8];
        #pragma unroll
        for (int ps = 0; ps < 4; ++ps)
            #pragma unroll
            for (int kf = 0; kf < 2; ++kf)
                xf[ps][kf] = *(const f16x8*)(xbase + (ps * 16 + fr) * 256
                                             + st * 64 + kf * 32 + fq * 8);
        __builtin_amdgcn_s_setprio(1);
        #pragma unroll
        for (int ls = 0; ls < 4; ++ls)
            #pragma unroll
            for (int ps = 0; ps < 4; ++ps) {
                Y[ls][ps] = __builtin_amdgcn_mfma_f32_16x16x32_f16(wf[ls][0], xf[ps][0], Y[ls][ps], 0, 0, 0);
                Y[ls][ps] = __builtin_amdgcn_mfma_f32_16x16x32_f16(wf[ls][1], xf[ps][1], Y[ls][ps], 0, 0, 0);
            }
        __builtin_amdgcn_s_setprio(0);
    }

    // D-term columns from xts: xd[ps][ls][j] = XT[ps*16+fr][w*64+ls*16+fq*4+j]
    f16x4 xd[4][4];
    #pragma unroll
    for (int ps = 0; ps < 4; ++ps)
        #pragma unroll
        for (int ls = 0; ls < 4; ++ls)
            xd[ps][ls] = *(const f16x4*)(xbase + (ps * 16 + fr) * 256
                                         + w * 64 + ls * 16 + fq * 4);

    float Dp = D_param[h];
    #pragma unroll
    for (int ls = 0; ls < 4; ++ls)
        #pragma unroll
        for (int r = 0; r < 4; ++r) {
            int ll = ls * 16 + fq * 4 + r;
            int l = w * 64 + ll;
            int tl = tbase + l;
            #pragma unroll
            for (int ps = 0; ps < 4; ++ps) {
                int p = ps * 16 + fr;
                float y = Y[ls][ps][r] + (float)xd[ps][ls][r] * Dp;
                float uv = (float)zf[(size_t)tl * D_INNER + h * HD + p] * fsilu(y);
                Wl[w][ll][p] = (_Float16)uv;
            }
        }
    {
        int l = w * 64 + lane;
        int tl = tbase + l;
        _Float16* dst = zf + (size_t)tl * D_INNER + h * HD;
        float ss = 0.f;
        #pragma unroll
        for (int i = 0; i < 8; ++i) {
            f16x8 v = *(const f16x8*)&Wl[w][lane][i * 8];
            *(f16x8*)(dst + i * 8) = v;
            #pragma unroll
            for (int j = 0; j < 8; ++j) { float f = (float)v[j]; ss += f * f; }
        }
        usq[(size_t)tl * 64 + h] = ss;
    }
}

extern "C" void kernel_launch(void* const* d_in, const int* in_sizes, int n_in,
                              void* d_out, int out_size, void* d_ws, size_t ws_size,
                              hipStream_t stream) {
    const float* x        = (const float*)d_in[0];
    const float* w_in     = (const float*)d_in[1];
    const float* conv_w   = (const float*)d_in[2];
    const float* conv_b   = (const float*)d_in[3];
    const float* dt_bias  = (const float*)d_in[4];
    const float* A_log    = (const float*)d_in[5];
    const float* D_param  = (const float*)d_in[6];
    const float* norm_w   = (const float*)d_in[7];
    const float* w_out    = (const float*)d_in[8];
    float* out = (float*)d_out;

    const size_t sz_zf  = (size_t)TTOK * D_INNER * 2;
    const size_t sz_cb  = (size_t)TTOK * XBC_DIM * 2;
    const size_t sz_x16 = (size_t)TTOK * D_MODEL * 2;
    const size_t sz_wi  = (size_t)N_ZX * D_MODEL * 2;
    const size_t sz_wo  = (size_t)D_MODEL * D_INNER * 2;
    const size_t sz_bc  = (size_t)TTOK * 128 * 2;
    const size_t sz_dt  = (size_t)TTOK * 64 * 4;
    const size_t sz_acs = (size_t)128 * LSEQ * 4;
    const size_t sz_st  = (size_t)1024 * 4096 * 4;
    const size_t need = sz_zf + sz_cb + sz_x16 + sz_wi + sz_wo
                      + sz_bc + sz_dt + sz_acs + sz_st;   // 155,713,536
    if (ws_size < need) return;

    char* p = (char*)d_ws;
    _Float16* zf     = (_Float16*)p; p += sz_zf;
    _Float16* cbuf   = (_Float16*)p; p += sz_cb;
    _Float16* x16    = (_Float16*)p; p += sz_x16;
    _Float16* win16  = (_Float16*)p; p += sz_wi;
    _Float16* wout16 = (_Float16*)p; p += sz_wo;
    _Float16* bc     = (_Float16*)p; p += sz_bc;
    float*    dtb    = (float*)p;    p += sz_dt;
    float*    acs    = (float*)p;    p += sz_acs;
    float*    states = (float*)p;    p += sz_st;
    float* usq = dtb;                    // alias: dt reads complete before usq writes
    _Float16* xts = (_Float16*)d_out;    // d_out scratch

    {
        size_t total8 = NX8 + NW8 + NO8;
        cvt_all_kernel<<<(u32)((total8 + 255) / 256), 256, 0, stream>>>(
            x, w_in, w_out, norm_w, x16, win16, wout16);
    }
    gemm_in_dt<<<256 + GEMM_IN_BLKS, 256, 0, stream>>>(
        x16, win16, zf, cbuf, x, w_in, dt_bias, dtb);
    scan_bc_kernel<<<1024 + 2048, 256, 0, stream>>>(
        dtb, A_log, acs, cbuf, conv_w, conv_b, bc);
    chunkstate_mfma<<<2 * NCH * NH, 256, 0, stream>>>(
        cbuf, bc, conv_w, conv_b, dtb, acs, states, xts);
    chunkscan_kernel<<<2 * NH, 256, 0, stream>>>(acs, states);
    ymerged_mfma<<<2 * NCH * NH, 256, 0, stream>>>(
        xts, bc, zf, dtb, acs, states, D_param, usq);
    gemm_out16<<<(D_MODEL / 128) * (TTOK / 128), 256, 0, stream>>>(zf, wout16, out, usq);
}

// Round 24
// 444.273 us; speedup vs baseline: 1.0093x; 1.0093x over previous
//
#include <hip/hip_runtime.h>
#include <math.h>

#define D_MODEL   2048
#define D_INNER   4096
#define XBC_DIM   4224
#define D_IN_PROJ 8384
#define N_ZX      8320
#define NH    64
#define HD    64
#define DS    64
#define LCH   256
#define NCH   8
#define LSEQ  2048
#define TTOK  4096
#define EPS_R 1.1920929e-07f

#define XT_S 264
#define WL_S 72
#define GEMM_IN_BLKS ((N_ZX / 128) * (TTOK / 128))   // 2080

typedef unsigned short u16;
typedef unsigned int   u32;
typedef _Float16 f16x8 __attribute__((ext_vector_type(8)));
typedef _Float16 f16x4 __attribute__((ext_vector_type(4)));
typedef float    f4v   __attribute__((ext_vector_type(4)));

__device__ __forceinline__ float4 f16_ld4(const _Float16* c, size_t idx) {
    f16x4 v = *(const f16x4*)(c + idx);
    return make_float4((float)v[0], (float)v[1], (float)v[2], (float)v[3]);
}
__device__ __forceinline__ f16x8 cvt8(float4 a, float4 b) {
    f16x8 r;
    r[0] = (_Float16)a.x; r[1] = (_Float16)a.y; r[2] = (_Float16)a.z; r[3] = (_Float16)a.w;
    r[4] = (_Float16)b.x; r[5] = (_Float16)b.y; r[6] = (_Float16)b.z; r[7] = (_Float16)b.w;
    return r;
}
__device__ __forceinline__ float fexp(float x)  { return __expf(x); }
__device__ __forceinline__ float fsilu(float x) { return x / (1.f + __expf(-x)); }
__device__ __forceinline__ int xcd_swz(int orig, int nwg) {
    int cpx = nwg >> 3;
    return (orig & 7) * cpx + (orig >> 3);
}
__device__ __forceinline__ void gload16(const _Float16* g, _Float16* l) {
    __builtin_amdgcn_global_load_lds(
        (const __attribute__((address_space(1))) u32*)g,
        (__attribute__((address_space(3))) u32*)l, 16, 0, 0);
}

// ---- one merged f32 -> f16 pre-conversion (x16 | win16 | wout16*nw) -----
#define NX8  ((size_t)TTOK * D_MODEL / 8)
#define NW8  ((size_t)N_ZX * D_MODEL / 8)
#define NO8  ((size_t)D_MODEL * D_INNER / 8)
__global__ __launch_bounds__(256) void cvt_all_kernel(const float* __restrict__ x,
                                                      const float* __restrict__ w_in,
                                                      const float* __restrict__ w_out,
                                                      const float* __restrict__ nw,
                                                      _Float16* __restrict__ x16,
                                                      _Float16* __restrict__ win16,
                                                      _Float16* __restrict__ wout16) {
    size_t i = (size_t)blockIdx.x * 256 + threadIdx.x;
    if (i < NX8) {
        size_t base = i * 8;
        float4 a = *(const float4*)(x + base);
        float4 b = *(const float4*)(x + base + 4);
        *(f16x8*)(x16 + base) = cvt8(a, b);
    } else if (i < NX8 + NW8) {
        size_t base = (i - NX8) * 8;
        float4 a = *(const float4*)(w_in + base);
        float4 b = *(const float4*)(w_in + base + 4);
        *(f16x8*)(win16 + base) = cvt8(a, b);
    } else if (i < NX8 + NW8 + NO8) {
        size_t base = (i - NX8 - NW8) * 8;
        int k = (int)(base & 4095);
        float4 a = *(const float4*)(w_out + base);
        float4 b = *(const float4*)(w_out + base + 4);
        float4 na = *(const float4*)(nw + k);
        float4 nb = *(const float4*)(nw + k + 4);
        a.x *= na.x; a.y *= na.y; a.z *= na.z; a.w *= na.w;
        b.x *= nb.x; b.y *= nb.y; b.z *= nb.z; b.w *= nb.w;
        *(f16x8*)(wout16 + base) = cvt8(a, b);
    }
}

// ===== UNION: dtproj (blocks 0..255) + in_proj GEMM (blocks 256..2335) ===
// GEMM tiles band-col-major per XCD (confirmed: FETCH 573->201 MB).
__global__ __launch_bounds__(256) void gemm_in_dt(const _Float16* __restrict__ A,
                                                  const _Float16* __restrict__ W,
                                                  _Float16* __restrict__ zf,
                                                  _Float16* __restrict__ cbuf,
                                                  const float* __restrict__ x,
                                                  const float* __restrict__ w_in,
                                                  const float* __restrict__ dt_bias,
                                                  float* __restrict__ dt_buf) {
    __shared__ __align__(16) char smem[65536];
    const int tid = threadIdx.x;

    if (blockIdx.x < 256) {
        float* Xs = (float*)smem;
        float* Ws = (float*)(smem + 4096);
        int t0 = blockIdx.x * 16;
        int h = tid & 63, trow = tid >> 6;
        float acc[4] = {0.f, 0.f, 0.f, 0.f};
        const float* wdt = w_in + (size_t)(D_INNER + XBC_DIM) * D_MODEL;

        for (int k0 = 0; k0 < D_MODEL; k0 += 64) {
            __syncthreads();
            {
                int r = tid >> 4, c4 = (tid & 15) * 4;
                *(float4*)&Xs[r * 64 + c4] =
                    *(const float4*)(x + (size_t)(t0 + r) * D_MODEL + k0 + c4);
            }
            #pragma unroll
            for (int i = 0; i < 4; ++i) {
                int ff = tid + i * 256;
                int r = ff >> 4, c4 = (ff & 15) * 4;
                float4 v = *(const float4*)(wdt + (size_t)r * D_MODEL + k0 + c4);
                Ws[r * 65 + c4 + 0] = v.x; Ws[r * 65 + c4 + 1] = v.y;
                Ws[r * 65 + c4 + 2] = v.z; Ws[r * 65 + c4 + 3] = v.w;
            }
            __syncthreads();
            #pragma unroll 16
            for (int k = 0; k < 64; ++k) {
                float wv = Ws[h * 65 + k];
                #pragma unroll
                for (int i = 0; i < 4; ++i)
                    acc[i] += Xs[(trow + i * 4) * 64 + k] * wv;
            }
        }
        float bias = dt_bias[h];
        #pragma unroll
        for (int i = 0; i < 4; ++i) {
            float xv = acc[i] + bias;
            float sp = (xv > 20.f) ? xv : log1pf(expf(xv));
            dt_buf[(size_t)(t0 + trow + i * 4) * 64 + h] = sp;
        }
        return;
    }

    _Float16* lsA = (_Float16*)smem;
    _Float16* lsB = (_Float16*)(smem + 32768);
    const int lane = tid & 63, w = tid >> 6;
    int swz = xcd_swz((int)blockIdx.x - 256, GEMM_IN_BLKS);
    int band = swz / 260, idx = swz % 260;
    const int row0 = (band * 4 + (idx & 3)) * 128;
    const int col0 = (idx >> 2) * 128;
    const int wr = w >> 1, wc = w & 1;
    const int fr = lane & 15, fq = lane >> 4;

    auto stage = [&](int buf, int k0) {
        #pragma unroll
        for (int i = 0; i < 4; ++i) {
            int obase = i * 4096 + w * 1024;
            int o = obase + lane * 16;
            int row = o >> 7, b0 = o & 127;
            int lb = b0 ^ ((row & 7) << 4);
            gload16(A + (size_t)(row0 + row) * D_MODEL + k0 + (lb >> 1),
                    lsA + buf * 8192 + (obase >> 1));
            gload16(W + (size_t)(col0 + row) * D_MODEL + k0 + (lb >> 1),
                    lsB + buf * 8192 + (obase >> 1));
        }
    };

    f4v acc[4][4];
    #pragma unroll
    for (int mi = 0; mi < 4; ++mi)
        #pragma unroll
        for (int ni = 0; ni < 4; ++ni) acc[mi][ni] = (f4v){0.f, 0.f, 0.f, 0.f};

    stage(0, 0);
    __syncthreads();
    int cur = 0;
    for (int k0 = 0; k0 < D_MODEL; k0 += 64) {
        if (k0 + 64 < D_MODEL) stage(cur ^ 1, k0 + 64);
        f16x8 ah[4][2];
        #pragma unroll
        for (int mi = 0; mi < 4; ++mi)
            #pragma unroll
            for (int kf = 0; kf < 2; ++kf) {
                int r = wr * 64 + mi * 16 + fr;
                int pb = (kf * 64 + fq * 16) ^ ((r & 7) << 4);
                ah[mi][kf] = *(const f16x8*)((const char*)lsA + cur * 16384 + r * 128 + pb);
            }
        #pragma unroll
        for (int ni = 0; ni < 4; ++ni) {
            #pragma unroll
            for (int kf = 0; kf < 2; ++kf) {
                int rb = wc * 64 + ni * 16 + fr;
                int pb = (kf * 64 + fq * 16) ^ ((rb & 7) << 4);
                f16x8 bh = *(const f16x8*)((const char*)lsB + cur * 16384 + rb * 128 + pb);
                #pragma unroll
                for (int mi = 0; mi < 4; ++mi)
                    acc[mi][ni] = __builtin_amdgcn_mfma_f32_16x16x32_f16(ah[mi][kf], bh, acc[mi][ni], 0, 0, 0);
            }
        }
        __syncthreads();
        cur ^= 1;
    }

    const int orow = fq * 4;
    #pragma unroll
    for (int mi = 0; mi < 4; ++mi)
        #pragma unroll
        for (int ni = 0; ni < 4; ++ni) {
            int r = row0 + wr * 64 + mi * 16 + orow;
            int cc = col0 + wc * 64 + ni * 16 + fr;
            if (col0 < D_INNER) {
                #pragma unroll
                for (int j = 0; j < 4; ++j)
                    zf[(size_t)(r + j) * D_INNER + cc] = (_Float16)acc[mi][ni][j];
            } else {
                #pragma unroll
                for (int j = 0; j < 4; ++j)
                    cbuf[(size_t)(r + j) * XBC_DIM + (cc - D_INNER)] = (_Float16)acc[mi][ni][j];
            }
        }
}

// ===== UNION: scan (blocks 0..1023) + bcconv (blocks 1024..3071) =========
__global__ __launch_bounds__(256) void scan_bc_kernel(const float* __restrict__ dt_buf,
                                                      const float* __restrict__ A_log,
                                                      float* __restrict__ acs,
                                                      const _Float16* __restrict__ cbuf,
                                                      const float* __restrict__ cw,
                                                      const float* __restrict__ cb,
                                                      _Float16* __restrict__ bc) {
    int tid = threadIdx.x;
    if (blockIdx.x < 1024) {
        int bh = blockIdx.x >> 3, c = blockIdx.x & 7;
        int b = bh >> 6, h = bh & 63;
        float Ah = -expf(A_log[h]);
        __shared__ float s[256];
        int t = b * LSEQ + c * LCH + tid;
        float a = Ah * dt_buf[t * 64 + h];
        s[tid] = a;
        __syncthreads();
        for (int off = 1; off < 256; off <<= 1) {
            float v = (tid >= off) ? s[tid - off] : 0.f;
            __syncthreads();
            s[tid] += v;
            __syncthreads();
        }
        acs[(size_t)bh * LSEQ + c * LCH + tid] = s[tid];
    } else {
        int t = ((int)blockIdx.x - 1024) * 2 + (tid >> 7);
        int chl = tid & 127;
        int b = t >> 11, lp = t & 2047;
        int ch = D_INNER + chl;
        float acc = cb[ch];
        #pragma unroll
        for (int j = 0; j < 4; ++j) {
            int lj = lp - 3 + j;
            if (lj >= 0)
                acc += cw[ch * 4 + j] * (float)cbuf[(size_t)(b * LSEQ + lj) * XBC_DIM + ch];
        }
        bc[(size_t)t * 128 + chl] = (_Float16)fsilu(acc);
    }
}

// out_proj with fused rstd; band-col-major mapping (512/8 = 64 = 4*16)
__global__ __launch_bounds__(256) void gemm_out16(const _Float16* __restrict__ A,
                                                  const _Float16* __restrict__ W,
                                                  float* __restrict__ C,
                                                  const float* __restrict__ usq) {
    __shared__ __align__(16) _Float16 lsA[2][128 * 64];
    __shared__ __align__(16) _Float16 lsB[2][128 * 64];
    __shared__ float rstd_l[128];
    const int tid = threadIdx.x, lane = tid & 63, w = tid >> 6;
    int swz = xcd_swz(blockIdx.x, (D_MODEL / 128) * (TTOK / 128));
    int band = swz / 64, idx = swz % 64;
    const int row0 = (band * 4 + (idx & 3)) * 128;
    const int col0 = (idx >> 2) * 128;
    const int wr = w >> 1, wc = w & 1;
    const int fr = lane & 15, fq = lane >> 4;

    auto stage = [&](int buf, int k0) {
        #pragma unroll
        for (int i = 0; i < 4; ++i) {
            int obase = i * 4096 + w * 1024;
            int o = obase + lane * 16;
            int row = o >> 7, b0 = o & 127;
            int lb = b0 ^ ((row & 7) << 4);
            gload16(A + (size_t)(row0 + row) * D_INNER + k0 + (lb >> 1), &lsA[buf][obase >> 1]);
            gload16(W + (size_t)(col0 + row) * D_INNER + k0 + (lb >> 1), &lsB[buf][obase >> 1]);
        }
    };

    if (tid < 128) {
        const float* uq = usq + (size_t)(row0 + tid) * 64;
        float s = 0.f;
        #pragma unroll
        for (int i = 0; i < 16; ++i) {
            float4 v = *(const float4*)(uq + i * 4);
            s += v.x + v.y + v.z + v.w;
        }
        rstd_l[tid] = rsqrtf(s / 4096.f + EPS_R);
    }

    f4v acc[4][4];
    #pragma unroll
    for (int mi = 0; mi < 4; ++mi)
        #pragma unroll
        for (int ni = 0; ni < 4; ++ni) acc[mi][ni] = (f4v){0.f, 0.f, 0.f, 0.f};

    stage(0, 0);
    __syncthreads();
    int cur = 0;
    for (int k0 = 0; k0 < D_INNER; k0 += 64) {
        if (k0 + 64 < D_INNER) stage(cur ^ 1, k0 + 64);
        f16x8 ah[4][2];
        #pragma unroll
        for (int mi = 0; mi < 4; ++mi)
            #pragma unroll
            for (int kf = 0; kf < 2; ++kf) {
                int r = wr * 64 + mi * 16 + fr;
                int pb = (kf * 64 + fq * 16) ^ ((r & 7) << 4);
                ah[mi][kf] = *(const f16x8*)((const char*)&lsA[cur][0] + r * 128 + pb);
            }
        #pragma unroll
        for (int ni = 0; ni < 4; ++ni) {
            #pragma unroll
            for (int kf = 0; kf < 2; ++kf) {
                int rb = wc * 64 + ni * 16 + fr;
                int pb = (kf * 64 + fq * 16) ^ ((rb & 7) << 4);
                f16x8 bh = *(const f16x8*)((const char*)&lsB[cur][0] + rb * 128 + pb);
                #pragma unroll
                for (int mi = 0; mi < 4; ++mi)
                    acc[mi][ni] = __builtin_amdgcn_mfma_f32_16x16x32_f16(ah[mi][kf], bh, acc[mi][ni], 0, 0, 0);
            }
        }
        __syncthreads();
        cur ^= 1;
    }

    const int orow = fq * 4;
    #pragma unroll
    for (int mi = 0; mi < 4; ++mi)
        #pragma unroll
        for (int ni = 0; ni < 4; ++ni) {
            int rl = wr * 64 + mi * 16 + orow;
            int cc = col0 + wc * 64 + ni * 16 + fr;
            #pragma unroll
            for (int j = 0; j < 4; ++j)
                C[(size_t)(row0 + rl + j) * D_MODEL + cc] = acc[mi][ni][j] * rstd_l[rl + j];
        }
}

// ===== MFMA chunk states + XT dump; wdec folded into BT ==================
__global__ __launch_bounds__(256) void chunkstate_mfma(const _Float16* __restrict__ cbuf,
                                                       const _Float16* __restrict__ bc,
                                                       const float* __restrict__ cw,
                                                       const float* __restrict__ cb,
                                                       const float* __restrict__ dt_buf,
                                                       const float* __restrict__ acs,
                                                       float* __restrict__ states,
                                                       _Float16* __restrict__ xts) {
    const int h = blockIdx.x & 63;
    const int c = (blockIdx.x >> 6) & 7;
    const int b = blockIdx.x >> 9;
    const int tbase = b * LSEQ + c * LCH;
    const int tid = threadIdx.x, lane = tid & 63, w = tid >> 6;
    const int fr = lane & 15, fq = lane >> 4;

    __shared__ __align__(16) _Float16 XT[64][XT_S];   // unweighted X^T
    __shared__ __align__(16) _Float16 BT[64][XT_S];   // wdec-weighted B^T
    __shared__ float acs_s[256], dts[256], wdec[256];

    const float* acs_blk = acs + (size_t)(b * 64 + h) * LSEQ + c * LCH;
    acs_s[tid] = acs_blk[tid];
    dts[tid] = dt_buf[(size_t)(tbase + tid) * 64 + h];
    __syncthreads();
    const float acs_last = acs_s[LCH - 1];
    wdec[tid] = fexp(acs_last - acs_s[tid]) * dts[tid];

    #pragma unroll 4
    for (int i = 0; i < 16; ++i) {
        int u = tid + i * 256;
        int s = u >> 4, pq = (u & 15) * 4;
        int lp = c * LCH + s;
        int ch0 = h * HD + pq;
        float tp[4][4];
        #pragma unroll
        for (int k = 0; k < 4; ++k)
            *(float4*)tp[k] = *(const float4*)(cw + (size_t)(ch0 + k) * 4);
        float a0 = cb[ch0], a1 = cb[ch0 + 1], a2 = cb[ch0 + 2], a3 = cb[ch0 + 3];
        #pragma unroll
        for (int j = 0; j < 4; ++j) {
            int lj = lp - 3 + j;
            if (lj >= 0) {
                float4 v = f16_ld4(cbuf, (size_t)(b * LSEQ + lj) * XBC_DIM + ch0);
                a0 += tp[0][j] * v.x; a1 += tp[1][j] * v.y;
                a2 += tp[2][j] * v.z; a3 += tp[3][j] * v.w;
            }
        }
        XT[pq + 0][s] = (_Float16)fsilu(a0);
        XT[pq + 1][s] = (_Float16)fsilu(a1);
        XT[pq + 2][s] = (_Float16)fsilu(a2);
        XT[pq + 3][s] = (_Float16)fsilu(a3);
    }
    __syncthreads();
    #pragma unroll 4
    for (int i = 0; i < 16; ++i) {
        int u = tid + i * 256;
        int s = u >> 4, n4 = (u & 15) * 4;
        f16x4 v = *(const f16x4*)(bc + (size_t)(tbase + s) * 128 + n4);
        float wd = wdec[s];
        BT[n4 + 0][s] = (_Float16)((float)v[0] * wd);
        BT[n4 + 1][s] = (_Float16)((float)v[1] * wd);
        BT[n4 + 2][s] = (_Float16)((float)v[2] * wd);
        BT[n4 + 3][s] = (_Float16)((float)v[3] * wd);
    }
    __syncthreads();

    f4v acc[4];
    #pragma unroll
    for (int nf = 0; nf < 4; ++nf) acc[nf] = (f4v){0.f, 0.f, 0.f, 0.f};
    __builtin_amdgcn_s_setprio(1);
    #pragma unroll
    for (int ks = 0; ks < 8; ++ks) {
        f16x8 af = *(const f16x8*)&XT[w * 16 + fr][ks * 32 + fq * 8];
        #pragma unroll
        for (int nf = 0; nf < 4; ++nf) {
            f16x8 bf = *(const f16x8*)&BT[nf * 16 + fr][ks * 32 + fq * 8];
            acc[nf] = __builtin_amdgcn_mfma_f32_16x16x32_f16(af, bf, acc[nf], 0, 0, 0);
        }
    }
    __builtin_amdgcn_s_setprio(0);
    float* sp = states + (size_t)blockIdx.x * 4096;
    #pragma unroll
    for (int nf = 0; nf < 4; ++nf)
        #pragma unroll
        for (int r = 0; r < 4; ++r)
            sp[(size_t)(w * 16 + fq * 4 + r) * 64 + nf * 16 + fr] = acc[nf][r];

    // dump unweighted XT to scratch for ymerged
    {
        _Float16* xd = xts + (size_t)blockIdx.x * 16384 + tid * 64;
        int pp = tid >> 2, s0 = (tid & 3) * 64;
        #pragma unroll
        for (int i = 0; i < 8; ++i)
            *(f16x8*)(xd + i * 8) = *(const f16x8*)&XT[pp][s0 + i * 8];
    }
}

// ----- inter-chunk recurrence per (b,h); in-place ------------------------
__global__ __launch_bounds__(256) void chunkscan_kernel(const float* __restrict__ acs,
                                                        float* __restrict__ states) {
    int b = blockIdx.x >> 6, h = blockIdx.x & 63;
    int tid = threadIdx.x;
    float4 S4[4];
    #pragma unroll
    for (int i = 0; i < 4; ++i) S4[i] = make_float4(0.f, 0.f, 0.f, 0.f);
    const float* acs_blk = acs + (size_t)blockIdx.x * LSEQ;
    for (int c = 0; c < NCH; ++c) {
        float d = expf(acs_blk[c * LCH + LCH - 1]);
        float4* sp = (float4*)(states + ((size_t)(b * NCH + c) * NH + h) * 4096 + tid * 16);
        float4 t4[4];
        #pragma unroll
        for (int i = 0; i < 4; ++i) t4[i] = sp[i];
        #pragma unroll
        for (int i = 0; i < 4; ++i) sp[i] = S4[i];
        #pragma unroll
        for (int i = 0; i < 4; ++i) {
            S4[i].x = d * S4[i].x + t4[i].x;
            S4[i].y = d * S4[i].y + t4[i].y;
            S4[i].z = d * S4[i].z + t4[i].z;
            S4[i].w = d * S4[i].w + t4[i].w;
        }
    }
}

// ===== MFMA ymerged (4-wave); XT in LDS; bc f16 direct frags =============
__global__ __launch_bounds__(256) void ymerged_mfma(const _Float16* __restrict__ xts,
                                                    const _Float16* __restrict__ bc,
                                                    _Float16* __restrict__ zf,
                                                    const float* __restrict__ dt_buf,
                                                    const float* __restrict__ acs,
                                                    const float* __restrict__ states,
                                                    const float* __restrict__ D_param,
                                                    float* __restrict__ usq) {
    const int h = blockIdx.x & 63;
    const int c = (blockIdx.x >> 6) & 7;
    const int b = blockIdx.x >> 9;
    const int tbase = b * LSEQ + c * LCH;
    const int tid = threadIdx.x, lane = tid & 63, w = tid >> 6;
    const int fr = lane & 15, fq = lane >> 4;

    __shared__ __align__(16) _Float16 XT[64][XT_S];
    __shared__ __align__(16) _Float16 Wl[4][64][WL_S];
    __shared__ float acs_s[256];
    __shared__ float dts[256];

    const float* acs_blk = acs + (size_t)(b * 64 + h) * LSEQ + c * LCH;
    acs_s[tid] = acs_blk[tid];
    dts[tid] = dt_buf[(size_t)(tbase + tid) * 64 + h];

    {
        const _Float16* xs = xts + (size_t)blockIdx.x * 16384 + tid * 64;
        int pp = tid >> 2, s0 = (tid & 3) * 64;
        #pragma unroll
        for (int i = 0; i < 8; ++i)
            *(f16x8*)&XT[pp][s0 + i * 8] = *(const f16x8*)(xs + i * 8);
    }
    __syncthreads();

    f16x8 cf[4][2];
    #pragma unroll
    for (int ls = 0; ls < 4; ++ls)
        #pragma unroll
        for (int kf = 0; kf < 2; ++kf)
            cf[ls][kf] = *(const f16x8*)(bc + (size_t)(tbase + w * 64 + ls * 16 + fr) * 128
                                         + 64 + kf * 32 + fq * 8);

    float acsl[16];
    #pragma unroll
    for (int ls = 0; ls < 4; ++ls)
        #pragma unroll
        for (int r = 0; r < 4; ++r)
            acsl[ls * 4 + r] = acs_s[w * 64 + ls * 16 + fq * 4 + r];

    f4v Y[4][4];
    {
        f16x8 sf[4][2];
        #pragma unroll
        for (int ps = 0; ps < 4; ++ps)
            #pragma unroll
            for (int kf = 0; kf < 2; ++kf) {
                const float* src = states + (size_t)blockIdx.x * 4096
                                 + (ps * 16 + fr) * 64 + kf * 32 + fq * 8;
                sf[ps][kf] = cvt8(*(const float4*)src, *(const float4*)(src + 4));
            }
        f4v yo[4][4];
        __builtin_amdgcn_s_setprio(1);
        #pragma unroll
        for (int ls = 0; ls < 4; ++ls)
            #pragma unroll
            for (int ps = 0; ps < 4; ++ps) {
                yo[ls][ps] = (f4v){0.f, 0.f, 0.f, 0.f};
                yo[ls][ps] = __builtin_amdgcn_mfma_f32_16x16x32_f16(cf[ls][0], sf[ps][0], yo[ls][ps], 0, 0, 0);
                yo[ls][ps] = __builtin_amdgcn_mfma_f32_16x16x32_f16(cf[ls][1], sf[ps][1], yo[ls][ps], 0, 0, 0);
            }
        __builtin_amdgcn_s_setprio(0);
        #pragma unroll
        for (int ls = 0; ls < 4; ++ls)
            #pragma unroll
            for (int ps = 0; ps < 4; ++ps)
                #pragma unroll
                for (int r = 0; r < 4; ++r)
                    Y[ls][ps][r] = fexp(acsl[ls * 4 + r]) * yo[ls][ps][r];
    }

    for (int st = 0; st <= w; ++st) {
        f16x8 bf[4][2];
        #pragma unroll
        for (int ss = 0; ss < 4; ++ss)
            #pragma unroll
            for (int kf = 0; kf < 2; ++kf)
                bf[ss][kf] = *(const f16x8*)(bc + (size_t)(tbase + st * 64 + ss * 16 + fr) * 128
                                             + kf * 32 + fq * 8);
        f4v S[4][4];
        __builtin_amdgcn_s_setprio(1);
        #pragma unroll
        for (int ls = 0; ls < 4; ++ls)
            #pragma unroll
            for (int ss = 0; ss < 4; ++ss) {
                S[ls][ss] = (f4v){0.f, 0.f, 0.f, 0.f};
                S[ls][ss] = __builtin_amdgcn_mfma_f32_16x16x32_f16(cf[ls][0], bf[ss][0], S[ls][ss], 0, 0, 0);
                S[ls][ss] = __builtin_amdgcn_mfma_f32_16x16x32_f16(cf[ls][1], bf[ss][1], S[ls][ss], 0, 0, 0);
            }
        __builtin_amdgcn_s_setprio(0);
        #pragma unroll
        for (int ss = 0; ss < 4; ++ss) {
            int s_idx = st * 64 + ss * 16 + fr;
            float as = acs_s[s_idx];
            float dv = dts[s_idx];
            #pragma unroll
            for (int ls = 0; ls < 4; ++ls)
                #pragma unroll
                for (int r = 0; r < 4; ++r) {
                    int l_idx = w * 64 + ls * 16 + fq * 4 + r;
                    float wv = (s_idx <= l_idx)
                             ? fexp(acsl[ls * 4 + r] - as) * dv * S[ls][ss][r] : 0.f;
                    Wl[w][ls * 16 + fq * 4 + r][ss * 16 + fr] = (_Float16)wv;
                }
        }
        f16x8 wf[4][2], xf[4][2];
        #pragma unroll
        for (int ls = 0; ls < 4; ++ls)
            #pragma unroll
            for (int kf = 0; kf < 2; ++kf)
                wf[ls][kf] = *(const f16x8*)&Wl[w][ls * 16 + fr][kf * 32 + fq * 8];
        #pragma unroll
        for (int ps = 0; ps < 4; ++ps)
            #pragma unroll
            for (int kf = 0; kf < 2; ++kf)
                xf[ps][kf] = *(const f16x8*)&XT[ps * 16 + fr][st * 64 + kf * 32 + fq * 8];
        __builtin_amdgcn_s_setprio(1);
        #pragma unroll
        for (int ls = 0; ls < 4; ++ls)
            #pragma unroll
            for (int ps = 0; ps < 4; ++ps) {
                Y[ls][ps] = __builtin_amdgcn_mfma_f32_16x16x32_f16(wf[ls][0], xf[ps][0], Y[ls][ps], 0, 0, 0);
                Y[ls][ps] = __builtin_amdgcn_mfma_f32_16x16x32_f16(wf[ls][1], xf[ps][1], Y[ls][ps], 0, 0, 0);
            }
        __builtin_amdgcn_s_setprio(0);
    }

    float Dp = D_param[h];
    #pragma unroll
    for (int ls = 0; ls < 4; ++ls)
        #pragma unroll
        for (int r = 0; r < 4; ++r) {
            int ll = ls * 16 + fq * 4 + r;
            int l = w * 64 + ll;
            int tl = tbase + l;
            #pragma unroll
            for (int ps = 0; ps < 4; ++ps) {
                int p = ps * 16 + fr;
                float y = Y[ls][ps][r] + (float)XT[p][l] * Dp;
                float uv = (float)zf[(size_t)tl * D_INNER + h * HD + p] * fsilu(y);
                Wl[w][ll][p] = (_Float16)uv;
            }
        }
    {
        int l = w * 64 + lane;
        int tl = tbase + l;
        _Float16* dst = zf + (size_t)tl * D_INNER + h * HD;
        float ss = 0.f;
        #pragma unroll
        for (int i = 0; i < 8; ++i) {
            f16x8 v = *(const f16x8*)&Wl[w][lane][i * 8];
            *(f16x8*)(dst + i * 8) = v;
            #pragma unroll
            for (int j = 0; j < 8; ++j) { float f = (float)v[j]; ss += f * f; }
        }
        usq[(size_t)tl * 64 + h] = ss;
    }
}

extern "C" void kernel_launch(void* const* d_in, const int* in_sizes, int n_in,
                              void* d_out, int out_size, void* d_ws, size_t ws_size,
                              hipStream_t stream) {
    const float* x        = (const float*)d_in[0];
    const float* w_in     = (const float*)d_in[1];
    const float* conv_w   = (const float*)d_in[2];
    const float* conv_b   = (const float*)d_in[3];
    const float* dt_bias  = (const float*)d_in[4];
    const float* A_log    = (const float*)d_in[5];
    const float* D_param  = (const float*)d_in[6];
    const float* norm_w   = (const float*)d_in[7];
    const float* w_out    = (const float*)d_in[8];
    float* out = (float*)d_out;

    const size_t sz_zf  = (size_t)TTOK * D_INNER * 2;
    const size_t sz_cb  = (size_t)TTOK * XBC_DIM * 2;
    const size_t sz_x16 = (size_t)TTOK * D_MODEL * 2;
    const size_t sz_wi  = (size_t)N_ZX * D_MODEL * 2;
    const size_t sz_wo  = (size_t)D_MODEL * D_INNER * 2;
    const size_t sz_bc  = (size_t)TTOK * 128 * 2;
    const size_t sz_dt  = (size_t)TTOK * 64 * 4;
    const size_t sz_acs = (size_t)128 * LSEQ * 4;
    const size_t sz_st  = (size_t)1024 * 4096 * 4;
    const size_t need = sz_zf + sz_cb + sz_x16 + sz_wi + sz_wo
                      + sz_bc + sz_dt + sz_acs + sz_st;   // 155,713,536
    if (ws_size < need) return;

    char* p = (char*)d_ws;
    _Float16* zf     = (_Float16*)p; p += sz_zf;
    _Float16* cbuf   = (_Float16*)p; p += sz_cb;
    _Float16* x16    = (_Float16*)p; p += sz_x16;
    _Float16* win16  = (_Float16*)p; p += sz_wi;
    _Float16* wout16 = (_Float16*)p; p += sz_wo;
    _Float16* bc     = (_Float16*)p; p += sz_bc;
    float*    dtb    = (float*)p;    p += sz_dt;
    float*    acs    = (float*)p;    p += sz_acs;
    float*    states = (float*)p;    p += sz_st;
    float* usq = dtb;                    // alias: dt reads complete before usq writes
    _Float16* xts = (_Float16*)d_out;    // d_out scratch

    {
        size_t total8 = NX8 + NW8 + NO8;
        cvt_all_kernel<<<(u32)((total8 + 255) / 256), 256, 0, stream>>>(
            x, w_in, w_out, norm_w, x16, win16, wout16);
    }
    gemm_in_dt<<<256 + GEMM_IN_BLKS, 256, 0, stream>>>(
        x16, win16, zf, cbuf, x, w_in, dt_bias, dtb);
    scan_bc_kernel<<<1024 + 2048, 256, 0, stream>>>(
        dtb, A_log, acs, cbuf, conv_w, conv_b, bc);
    chunkstate_mfma<<<2 * NCH * NH, 256, 0, stream>>>(
        cbuf, bc, conv_w, conv_b, dtb, acs, states, xts);
    chunkscan_kernel<<<2 * NH, 256, 0, stream>>>(acs, states);
    ymerged_mfma<<<2 * NCH * NH, 256, 0, stream>>>(
        xts, bc, zf, dtb, acs, states, D_param, usq);
    gemm_out16<<<(D_MODEL / 128) * (TTOK / 128), 256, 0, stream>>>(zf, wout16, out, usq);
}